// Round 10
// baseline (606.738 us; speedup 1.0000x reference)
//
#include <hip/hip_runtime.h>

// WindowAttention v10 for MI355X (gfx950) — two-kernel split.
// B=4096 windows, N=49, C=256, H=8, hd=32. fp32 in/out, f16 MFMA inside.
//
// r1-r9 lesson: the fully-fused 8-wave/76KB-LDS mono-kernel is latency-bound
// on its serial phase chain (occ 23-45% made no difference; ~5% MFMA util).
// v10: K1 = QKV+attention, 256-thr blocks (4 waves, wave owns 2 heads
// sequentially), LDS 51KB -> 3 independent blocks/CU (12 waves), ONE barrier;
// ao written f16 to global ws. K2 = out-projection GEMM (M=200704, N=K=256),
// 128-row tiles. launch_bounds(256,3) is semantics-proof (both readings give
// a ~170-reg cap >= ~150 demand -> zero spill at 3 waves/SIMD).

#define NTOK 49
#define XPAD 264
#define PPAD 264
#define SCALE_F 0.17677669529663687f

typedef _Float16 v8h __attribute__((ext_vector_type(8)));
typedef _Float16 v4h __attribute__((ext_vector_type(4)));
typedef float    v4f __attribute__((ext_vector_type(4)));
typedef int      v4i __attribute__((ext_vector_type(4)));

__device__ __forceinline__ v8h ldsv8(const _Float16* p) { return *(const v8h*)p; }
__device__ __forceinline__ int packh2(float lo, float hi) {
    unsigned short a = __builtin_bit_cast(unsigned short, (_Float16)lo);
    unsigned short b = __builtin_bit_cast(unsigned short, (_Float16)hi);
    return (int)((unsigned)a | ((unsigned)b << 16));
}

// ---------------- prep: f16 weights + float4-packed bias rows ----------------
__global__ void wa_prep(const float* __restrict__ Wq, const float* __restrict__ Wk,
                        const float* __restrict__ Wv, const float* __restrict__ Wp,
                        const float* __restrict__ bias_table, const int* __restrict__ rel_idx,
                        _Float16* __restrict__ wqkv, _Float16* __restrict__ wp,
                        float* __restrict__ biasm2) {
    int t = blockIdx.x * blockDim.x + threadIdx.x;
    const int NW = 768 * 256;
    const int NP = 256 * 256;
    const int NB4 = 8 * NTOK * 16;        // float4 units
    if (t < NW) {
        int n = t >> 8, k = t & 255;
        const float* W = (n < 256) ? Wq : (n < 512 ? Wk : Wv);
        wqkv[t] = (_Float16)W[(n & 255) * 256 + k];
    } else if (t < NW + NP) {
        int u = t - NW;
        wp[u] = (_Float16)Wp[u];
    } else if (t < NW + NP + NB4) {
        int u = t - NW - NP;               // (h*49 + row)*16 + fr
        int fr = u & 15;
        int hr = u >> 4;
        int row = hr % NTOK;
        int h = hr / NTOK;
        float4 v;
        float* vp = &v.x;
        #pragma unroll
        for (int c = 0; c < 4; ++c) {
            int col = fr + 16 * c;
            vp[c] = (col < NTOK) ? bias_table[rel_idx[row * NTOK + col] * 8 + h] : 0.f;
        }
        ((float4*)biasm2)[u] = v;
    }
}

// ---------------- K1: QKV + attention, ao -> global f16 ----------------
__global__ __launch_bounds__(256, 3) void wa_attn(
    const float* __restrict__ x,
    const float* __restrict__ bq, const float* __restrict__ bk,
    const float* __restrict__ bv,
    const _Float16* __restrict__ wqkv,
    const float* __restrict__ biasm2,
    _Float16* __restrict__ ao) {

    __shared__ _Float16 xs[NTOK * XPAD];     // 25,872 B (read-only after stage)
    __shared__ _Float16 arena[4 * 3136];     // 25,088 B (per-wave q|k -> P)

    const int b    = blockIdx.x;
    const int tid  = threadIdx.x;
    const int wid  = tid >> 6;               // 0..3
    const int lane = tid & 63;
    const int g    = lane >> 4;
    const int fr   = lane & 15;

    // ---- stage x -> f16 LDS (the ONLY barrier in this kernel) ----
    const float* xb = x + (size_t)b * (NTOK * 256);
    for (int i = tid; i < (NTOK * 256) / 4; i += 256) {
        float4 f = ((const float4*)xb)[i];
        int e = i * 4;
        v4h pk;
        pk[0] = (_Float16)f.x; pk[1] = (_Float16)f.y;
        pk[2] = (_Float16)f.z; pk[3] = (_Float16)f.w;
        *(v4h*)&xs[(e >> 8) * XPAD + (e & 255)] = pk;
    }
    __syncthreads();

    const v4f vzero = {0.f, 0.f, 0.f, 0.f};
    _Float16* wa = &arena[wid * 3136];
    _Float16* ob = ao + (size_t)b * (NTOK * 256);

    #pragma unroll 1
    for (int hi = 0; hi < 2; ++hi) {
        const int hh = 2 * wid + hi;         // this wave's head
        const int WB = hh * 32;

        // ---- q+k in ONE A-sweep (4 n-tiles, 64 accums) ----
        {
            v4f acc[4][4];
            #pragma unroll
            for (int t = 0; t < 4; ++t)
                #pragma unroll
                for (int mt = 0; mt < 4; ++mt) acc[t][mt] = vzero;
            #pragma unroll
            for (int ks = 0; ks < 8; ++ks) {
                v8h a[4];
                #pragma unroll
                for (int mt = 0; mt < 4; ++mt) {
                    int row = mt * 16 + fr; row = row > 48 ? 48 : row;
                    a[mt] = ldsv8(&xs[row * XPAD + ks * 32 + g * 8]);
                }
                #pragma unroll
                for (int t = 0; t < 4; ++t) {
                    int n = (t < 2) ? (WB + 16 * t + fr) : (256 + WB + 16 * (t - 2) + fr);
                    v8h bf = *(const v8h*)&wqkv[n * 256 + ks * 32 + g * 8];
                    #pragma unroll
                    for (int mt = 0; mt < 4; ++mt)
                        acc[t][mt] = __builtin_amdgcn_mfma_f32_16x16x32_f16(a[mt], bf, acc[t][mt], 0, 0, 0);
                }
            }
            #pragma unroll
            for (int t = 0; t < 4; ++t) {
                float bias = (t < 2) ? bq[WB + 16 * t + fr] : bk[WB + 16 * (t - 2) + fr];
                float scl  = (t < 2) ? SCALE_F : 1.f;
                int   base = (t < 2) ? 0 : 1568;
                int   d    = 16 * (t & 1) + fr;
                #pragma unroll
                for (int mt = 0; mt < 4; ++mt)
                    #pragma unroll
                    for (int r = 0; r < 4; ++r) {
                        int tok = mt * 16 + 4 * g + r;
                        if (tok < NTOK) {
                            int ch = (d >> 3) ^ ((tok >> 2) & 3);
                            wa[base + tok * 32 + ch * 8 + (d & 7)] = (_Float16)((acc[t][mt][r] + bias) * scl);
                        }
                    }
            }
        }
        asm volatile("s_waitcnt lgkmcnt(0)" ::: "memory");   // q/k written
        __builtin_amdgcn_sched_barrier(0);

        // ---- QK^T + softmax + P (pre-normalized) ----
        {
            v8h ap4[4], bk4[4];
            #pragma unroll
            for (int t = 0; t < 4; ++t) {
                int row = t * 16 + fr; row = row > 48 ? 48 : row;
                int c = (row >> 2) & 3;
                ap4[t] = ldsv8(&wa[row * 32 + (g ^ c) * 8]);
                bk4[t] = ldsv8(&wa[1568 + row * 32 + (g ^ c) * 8]);
            }
            asm volatile("s_waitcnt lgkmcnt(0)" ::: "memory");  // frags in regs before P overwrite
            __builtin_amdgcn_sched_barrier(0);

            #pragma unroll
            for (int mt = 0; mt < 4; ++mt) {
                v4f s[4];
                #pragma unroll
                for (int nt = 0; nt < 4; ++nt)
                    s[nt] = __builtin_amdgcn_mfma_f32_16x16x32_f16(ap4[mt], bk4[nt], vzero, 0, 0, 0);
                #pragma unroll
                for (int r = 0; r < 4; ++r) {
                    int row  = mt * 16 + 4 * g + r;
                    int brow = row > 48 ? 48 : row;
                    float4 b4 = ((const float4*)biasm2)[(hh * NTOK + brow) * 16 + fr];
                    const float* bp4 = &b4.x;
                    // constant-shift softmax: |s+bias| <~ 10 -> exp(val-12)
                    // finite/normal; normalization cancels the shift exactly.
                    float sum = 0.f;
                    #pragma unroll
                    for (int nt = 0; nt < 4; ++nt) {
                        float val = s[nt][r] + bp4[nt];
                        if (nt == 3 && fr > 0) val = -1.0e30f;   // col >= 49
                        float p = __expf(val - 12.0f);
                        s[nt][r] = p;
                        sum += p;
                    }
                    #pragma unroll
                    for (int off = 1; off < 16; off <<= 1) sum += __shfl_xor(sum, off);
                    float inv = __builtin_amdgcn_rcpf(sum);
                    if (row < NTOK) {
                        #pragma unroll
                        for (int nt = 0; nt < 4; ++nt) {
                            int col = nt * 16 + fr;
                            wa[row * 64 + (col ^ ((row & 7) << 3))] = (_Float16)(s[nt][r] * inv);
                        }
                    }
                }
            }
        }

        // ---- v projection (swapped operands -> D holds v^T) + in-reg transpose ----
        v4i vT4[2][2];
        {
            v4f av[2][4];
            #pragma unroll
            for (int vl = 0; vl < 2; ++vl)
                #pragma unroll
                for (int mt = 0; mt < 4; ++mt) av[vl][mt] = vzero;
            #pragma unroll
            for (int ks = 0; ks < 8; ++ks) {
                v8h a[4];
                #pragma unroll
                for (int mt = 0; mt < 4; ++mt) {
                    int row = mt * 16 + fr; row = row > 48 ? 48 : row;
                    a[mt] = ldsv8(&xs[row * XPAD + ks * 32 + g * 8]);
                }
                #pragma unroll
                for (int vl = 0; vl < 2; ++vl) {
                    v8h bf = *(const v8h*)&wqkv[(512 + WB + 16 * vl + fr) * 256 + ks * 32 + g * 8];
                    #pragma unroll
                    for (int mt = 0; mt < 4; ++mt)
                        av[vl][mt] = __builtin_amdgcn_mfma_f32_16x16x32_f16(a[mt], bf, av[vl][mt], 0, 0, 0);
                }
            }
            float bvv[2];
            bvv[0] = bv[WB + fr]; bvv[1] = bv[WB + 16 + fr];
            int pkv[2][4][2];
            #pragma unroll
            for (int vl = 0; vl < 2; ++vl)
                #pragma unroll
                for (int mt = 0; mt < 4; ++mt)
                    #pragma unroll
                    for (int p = 0; p < 2; ++p) {
                        int tl = mt * 16 + 4 * g + 2 * p;
                        float lo = (tl     < NTOK) ? av[vl][mt][2 * p]     + bvv[vl] : 0.f;
                        float hi = (tl + 1 < NTOK) ? av[vl][mt][2 * p + 1] + bvv[vl] : 0.f;
                        pkv[vl][mt][p] = packh2(lo, hi);
                    }
            int addrA = 4 * (16 * ((2 * g) & 3) + fr);       // target words 0,1
            int addrB = 4 * (16 * ((2 * g + 1) & 3) + fr);   // target words 2,3
            #pragma unroll
            for (int ntd = 0; ntd < 2; ++ntd)
                #pragma unroll
                for (int ks = 0; ks < 2; ++ks)
                    #pragma unroll
                    for (int w = 0; w < 4; ++w) {
                        int ad = (w < 2) ? addrA : addrB;
                        int b0 = __builtin_amdgcn_ds_bpermute(ad, pkv[ntd][2 * ks][w & 1]);
                        int b1 = __builtin_amdgcn_ds_bpermute(ad, pkv[ntd][2 * ks + 1][w & 1]);
                        vT4[ntd][ks][w] = (g < 2) ? b0 : b1;
                    }
        }
        asm volatile("s_waitcnt lgkmcnt(0)" ::: "memory");   // P writes drained before PV reads
        __builtin_amdgcn_sched_barrier(0);

        // ---- PV -> ao (global f16) ----
        {
            v4f o[4][2];
            #pragma unroll
            for (int mt = 0; mt < 4; ++mt) { o[mt][0] = vzero; o[mt][1] = vzero; }
            #pragma unroll
            for (int mt = 0; mt < 4; ++mt) {
                int row = mt * 16 + fr; row = row > 48 ? 48 : row;
                int r7 = row & 7;
                #pragma unroll
                for (int ks = 0; ks < 2; ++ks) {
                    v8h ap = ldsv8(&wa[row * 64 + ((4 * ks + g) ^ r7) * 8]);
                    #pragma unroll
                    for (int ntd = 0; ntd < 2; ++ntd) {
                        v8h bvv8 = __builtin_bit_cast(v8h, vT4[ntd][ks]);
                        o[mt][ntd] = __builtin_amdgcn_mfma_f32_16x16x32_f16(ap, bvv8, o[mt][ntd], 0, 0, 0);
                    }
                }
            }
            #pragma unroll
            for (int mt = 0; mt < 4; ++mt)
                #pragma unroll
                for (int r = 0; r < 4; ++r) {
                    int tok = mt * 16 + 4 * g + r;
                    if (tok < NTOK) {
                        #pragma unroll
                        for (int ntd = 0; ntd < 2; ++ntd)
                            ob[tok * 256 + WB + 16 * ntd + fr] = (_Float16)o[mt][ntd][r];
                    }
                }
        }
        asm volatile("s_waitcnt lgkmcnt(0)" ::: "memory");   // PV frag reads done before next head's arena writes
        __builtin_amdgcn_sched_barrier(0);
    }
}

// ---------------- K2: out = ao @ Wp^T + bp  (M=200704, N=K=256) ----------------
__global__ __launch_bounds__(512) void wa_proj(
    const _Float16* __restrict__ ao, const _Float16* __restrict__ wp,
    const float* __restrict__ bp, float* __restrict__ out) {

    __shared__ _Float16 as[128 * PPAD];      // 67,584 B, padded stride vs bank conflicts

    const int mb   = blockIdx.x;             // 1568 tiles of 128 rows (exact)
    const int tid  = threadIdx.x;
    const int wid  = tid >> 6;               // 0..7
    const int lane = tid & 63;
    const int g    = lane >> 4;
    const int fr   = lane & 15;

    // stage 128x256 f16 tile
    const _Float16* ab = ao + (size_t)mb * (128 * 256);
    for (int i = tid; i < (128 * 256) / 8; i += 512) {
        v8h v = *(const v8h*)&ab[i * 8];
        int e = i * 8;
        *(v8h*)&as[(e >> 8) * PPAD + (e & 255)] = v;
    }
    __syncthreads();

    const v4f vzero = {0.f, 0.f, 0.f, 0.f};
    v4f acc[2][8];
    #pragma unroll
    for (int ntl = 0; ntl < 2; ++ntl)
        #pragma unroll
        for (int mt = 0; mt < 8; ++mt) acc[ntl][mt] = vzero;

    #pragma unroll
    for (int ks = 0; ks < 8; ++ks) {
        v8h a[8];
        #pragma unroll
        for (int mt = 0; mt < 8; ++mt)
            a[mt] = ldsv8(&as[(mt * 16 + fr) * PPAD + ks * 32 + g * 8]);
        #pragma unroll
        for (int ntl = 0; ntl < 2; ++ntl) {
            int n = wid * 32 + 16 * ntl + fr;
            v8h bf = *(const v8h*)&wp[n * 256 + ks * 32 + g * 8];
            #pragma unroll
            for (int mt = 0; mt < 8; ++mt)
                acc[ntl][mt] = __builtin_amdgcn_mfma_f32_16x16x32_f16(a[mt], bf, acc[ntl][mt], 0, 0, 0);
        }
    }

    float* ob = out + (size_t)mb * (128 * 256);
    #pragma unroll
    for (int ntl = 0; ntl < 2; ++ntl) {
        int n = wid * 32 + 16 * ntl + fr;
        float bpn = bp[n];
        #pragma unroll
        for (int mt = 0; mt < 8; ++mt)
            #pragma unroll
            for (int r = 0; r < 4; ++r)
                ob[(mt * 16 + 4 * g + r) * 256 + n] = acc[ntl][mt][r] + bpn;
    }
}

extern "C" void kernel_launch(void* const* d_in, const int* in_sizes, int n_in,
                              void* d_out, int out_size, void* d_ws, size_t ws_size,
                              hipStream_t stream) {
    const float* x          = (const float*)d_in[0];
    const float* bias_table = (const float*)d_in[1];
    const float* Wq         = (const float*)d_in[2];
    const float* bq         = (const float*)d_in[3];
    const float* Wk         = (const float*)d_in[4];
    const float* bk         = (const float*)d_in[5];
    const float* Wv         = (const float*)d_in[6];
    const float* bv         = (const float*)d_in[7];
    const float* Wp         = (const float*)d_in[8];
    const float* bp         = (const float*)d_in[9];
    const int*   rel_idx    = (const int*)d_in[10];
    float* out = (float*)d_out;

    // ws layout (bytes):
    //   wqkv f16 [768*256]        @ 0        (393,216)
    //   wp   f16 [256*256]        @ 393216   (131,072)
    //   biasm2 f32 [8*49*16*4]    @ 524288   (100,352)
    //   ao   f16 [200704*256]     @ 624640   (102,760,448)   total ~103.4 MB
    _Float16* wqkv   = (_Float16*)d_ws;
    _Float16* wp     = wqkv + 768 * 256;
    float*    biasm2 = (float*)(wp + 256 * 256);
    _Float16* ao     = (_Float16*)((char*)d_ws + 624640);

    const int TOT = 768 * 256 + 256 * 256 + 8 * NTOK * 16;
    wa_prep<<<(TOT + 255) / 256, 256, 0, stream>>>(Wq, Wk, Wv, Wp, bias_table, rel_idx,
                                                   wqkv, wp, biasm2);
    wa_attn<<<4096, 256, 0, stream>>>(x, bq, bk, bv, wqkv, biasm2, ao);
    wa_proj<<<1568, 512, 0, stream>>>(ao, wp, bp, out);
}

// Round 11
// 519.403 us; speedup vs baseline: 1.1681x; 1.1681x over previous
//
#include <hip/hip_runtime.h>

// WindowAttention v11 for MI355X (gfx950) — 4-kernel short-chain pipeline.
// B=4096, N=49, C=256, H=8, hd=32. fp32 in/out, f16 MFMA inside.
//
// r10 lessons: (a) long per-wave phase chains dominate (v10 K1: 2x chain ->
// 545us); (b) wa_proj's shape (short chain, many independent blocks) runs at
// its HBM floor (~55us); (c) reg model: pool 512/SIMD, launch_bounds 2nd arg
// = min waves/EU, cap = 512/arg.
// v11: wa_qkv (GEMM M=200704 N=768, q/k/v to global f16) -> wa_attn2 (1 wave
// = 1 (window,head), NO barriers, q/k direct-from-global fragments, v via
// tiny per-wave LDS transpose, P via per-wave swizzled LDS) -> wa_proj
// (proven). Every wave chain is short; every kernel has thousands of
// independent blocks.

#define NTOK 49
#define PPAD 264
#define SCALE_F 0.17677669529663687f

typedef _Float16 v8h __attribute__((ext_vector_type(8)));
typedef _Float16 v4h __attribute__((ext_vector_type(4)));
typedef float    v4f __attribute__((ext_vector_type(4)));
typedef int      v4i __attribute__((ext_vector_type(4)));

__device__ __forceinline__ v8h ldsv8(const _Float16* p) { return *(const v8h*)p; }

// ---------------- prep: f16 weights + float4-packed bias rows ----------------
__global__ void wa_prep(const float* __restrict__ Wq, const float* __restrict__ Wk,
                        const float* __restrict__ Wv, const float* __restrict__ Wp,
                        const float* __restrict__ bias_table, const int* __restrict__ rel_idx,
                        _Float16* __restrict__ wqkv, _Float16* __restrict__ wp,
                        float* __restrict__ biasm2) {
    int t = blockIdx.x * blockDim.x + threadIdx.x;
    const int NW = 768 * 256;
    const int NP = 256 * 256;
    const int NB4 = 8 * NTOK * 16;
    if (t < NW) {
        int n = t >> 8, k = t & 255;
        const float* W = (n < 256) ? Wq : (n < 512 ? Wk : Wv);
        wqkv[t] = (_Float16)W[(n & 255) * 256 + k];
    } else if (t < NW + NP) {
        int u = t - NW;
        wp[u] = (_Float16)Wp[u];
    } else if (t < NW + NP + NB4) {
        int u = t - NW - NP;               // (h*49 + row)*16 + fr
        int fr = u & 15;
        int hr = u >> 4;
        int row = hr % NTOK;
        int h = hr / NTOK;
        float4 v;
        float* vp = &v.x;
        #pragma unroll
        for (int c = 0; c < 4; ++c) {
            int col = fr + 16 * c;
            vp[c] = (col < NTOK) ? bias_table[rel_idx[row * NTOK + col] * 8 + h] : 0.f;
        }
        ((float4*)biasm2)[u] = v;
    }
}

// ---------------- K1: qkv GEMM, M=200704 N=768 K=256 ----------------
// grid (3136, 3): 64-row M tiles; y selects q/k/v weight block + epilogue.
__global__ __launch_bounds__(512, 5) void wa_qkv(
    const float* __restrict__ x,
    const float* __restrict__ bq, const float* __restrict__ bk,
    const float* __restrict__ bv,
    const _Float16* __restrict__ wqkv,
    _Float16* __restrict__ qg, _Float16* __restrict__ kg, _Float16* __restrict__ vg) {

    __shared__ _Float16 as[64 * PPAD];       // 33,792 B -> 2 blocks/CU (with reg cap 102)

    const int mb   = blockIdx.x;             // 64-row tile
    const int y    = blockIdx.y;             // 0:q 1:k 2:v
    const int tid  = threadIdx.x;
    const int wid  = tid >> 6;
    const int lane = tid & 63;
    const int g    = lane >> 4;
    const int fr   = lane & 15;

    // stage 64x256 f32 -> f16
    const float* xb = x + (size_t)mb * (64 * 256);
    for (int i = tid; i < (64 * 256) / 4; i += 512) {
        float4 f = ((const float4*)xb)[i];
        int e = i * 4;
        v4h pk;
        pk[0] = (_Float16)f.x; pk[1] = (_Float16)f.y;
        pk[2] = (_Float16)f.z; pk[3] = (_Float16)f.w;
        *(v4h*)&as[(e >> 8) * PPAD + (e & 255)] = pk;
    }
    __syncthreads();

    const v4f vzero = {0.f, 0.f, 0.f, 0.f};
    v4f acc[2][4];
    #pragma unroll
    for (int ntl = 0; ntl < 2; ++ntl)
        #pragma unroll
        for (int mt = 0; mt < 4; ++mt) acc[ntl][mt] = vzero;

    #pragma unroll
    for (int ks = 0; ks < 8; ++ks) {
        v8h a[4];
        #pragma unroll
        for (int mt = 0; mt < 4; ++mt)
            a[mt] = ldsv8(&as[(mt * 16 + fr) * PPAD + ks * 32 + g * 8]);
        #pragma unroll
        for (int ntl = 0; ntl < 2; ++ntl) {
            int n = y * 256 + wid * 32 + 16 * ntl + fr;
            v8h bf = *(const v8h*)&wqkv[n * 256 + ks * 32 + g * 8];
            #pragma unroll
            for (int mt = 0; mt < 4; ++mt)
                acc[ntl][mt] = __builtin_amdgcn_mfma_f32_16x16x32_f16(a[mt], bf, acc[ntl][mt], 0, 0, 0);
        }
    }

    const float* bias_p = (y == 0) ? bq : (y == 1) ? bk : bv;
    const float  scl    = (y == 0) ? SCALE_F : 1.f;
    _Float16*    dst    = (y == 0) ? qg : (y == 1) ? kg : vg;
    #pragma unroll
    for (int ntl = 0; ntl < 2; ++ntl) {
        int nl = wid * 32 + 16 * ntl + fr;   // 0..255
        float bn = bias_p[nl];
        int h = nl >> 5, d = nl & 31;
        #pragma unroll
        for (int mt = 0; mt < 4; ++mt)
            #pragma unroll
            for (int r = 0; r < 4; ++r) {
                int row = mb * 64 + mt * 16 + 4 * g + r;   // < 200704
                int b   = row / 49;
                int tok = row - b * 49;
                dst[((size_t)(b * 8 + h)) * (NTOK * 32) + tok * 32 + d] =
                    (_Float16)((acc[ntl][mt][r] + bn) * scl);
            }
    }
}

// ---------------- K2: attention, 1 wave = 1 (window,head), NO barriers ----------------
#define AW (32 * 64 + NTOK * 64)   // per-wave arena halfs: vT[32][64] + P[49][64] = 5184
__global__ __launch_bounds__(256, 4) void wa_attn2(
    const _Float16* __restrict__ qg, const _Float16* __restrict__ kg,
    const _Float16* __restrict__ vg, const float* __restrict__ biasm2,
    _Float16* __restrict__ ao) {

    __shared__ _Float16 arena[4 * AW];       // 41,472 B -> 3 blocks/CU

    const int tid  = threadIdx.x;
    const int wid  = tid >> 6;
    const int lane = tid & 63;
    const int g    = lane >> 4;
    const int fr   = lane & 15;
    const int bh   = blockIdx.x * 4 + wid;   // 0..32767
    const int b    = bh >> 3, h = bh & 7;

    _Float16* vT = &arena[wid * AW];         // [32][64], XOR-swizzled tok
    _Float16* P  = vT + 32 * 64;             // [49][64], v8 swizzle

    const _Float16* qb = qg + (size_t)bh * (NTOK * 32);
    const _Float16* kb = kg + (size_t)bh * (NTOK * 32);
    const _Float16* vb = vg + (size_t)bh * (NTOK * 32);

    // ---- stage v -> vT[d][tok ^ ((d&7)<<3)], zero-pad toks 49..63 ----
    const v4i izero = {0, 0, 0, 0};
    #pragma unroll
    for (int it = 0; it < 4; ++it) {
        int idx = it * 64 + lane;            // 256 slots of 8 halfs = [64 tok][4 d-groups]
        int tok = idx >> 2;                  // 0..63
        int d0  = (idx & 3) * 8;
        v8h v = __builtin_bit_cast(v8h, izero);
        if (tok < NTOK) v = *(const v8h*)&vb[tok * 32 + d0];
        #pragma unroll
        for (int j = 0; j < 8; ++j)
            vT[(d0 + j) * 64 + (tok ^ (j << 3))] = v[j];
    }

    // ---- q,k fragments straight from global ([tok][d] == fragment layout) ----
    v8h aq[4], bk4[4];
    #pragma unroll
    for (int t = 0; t < 4; ++t) {
        int row = t * 16 + fr; row = row > 48 ? 48 : row;
        aq[t]  = *(const v8h*)&qb[row * 32 + g * 8];
        bk4[t] = *(const v8h*)&kb[row * 32 + g * 8];
    }

    // ---- QK^T + softmax + P (pre-normalized), per-mt ----
    const v4f vzero = {0.f, 0.f, 0.f, 0.f};
    #pragma unroll
    for (int mt = 0; mt < 4; ++mt) {
        v4f s[4];
        #pragma unroll
        for (int nt = 0; nt < 4; ++nt)
            s[nt] = __builtin_amdgcn_mfma_f32_16x16x32_f16(aq[mt], bk4[nt], vzero, 0, 0, 0);
        #pragma unroll
        for (int r = 0; r < 4; ++r) {
            int row  = mt * 16 + 4 * g + r;
            int brow = row > 48 ? 48 : row;
            float4 b4 = ((const float4*)biasm2)[(h * NTOK + brow) * 16 + fr];
            const float* bp4 = &b4.x;
            // constant-shift softmax (|s+bias| <~ 10): exp(val-12), shift cancels
            float sum = 0.f;
            #pragma unroll
            for (int nt = 0; nt < 4; ++nt) {
                float val = s[nt][r] + bp4[nt];
                if (nt == 3 && fr > 0) val = -1.0e30f;   // col >= 49
                float p = __expf(val - 12.0f);
                s[nt][r] = p;
                sum += p;
            }
            #pragma unroll
            for (int off = 1; off < 16; off <<= 1) sum += __shfl_xor(sum, off);
            float inv = __builtin_amdgcn_rcpf(sum);
            if (row < NTOK) {
                #pragma unroll
                for (int nt = 0; nt < 4; ++nt) {
                    int col = nt * 16 + fr;
                    P[row * 64 + (col ^ ((row & 7) << 3))] = (_Float16)(s[nt][r] * inv);
                }
            }
        }
    }
    // drain in-wave LDS writes (vT + P) before PV reads; wave-private arena
    asm volatile("s_waitcnt lgkmcnt(0)" ::: "memory");
    __builtin_amdgcn_sched_barrier(0);

    // ---- PV ----
    v8h bvf[2][2];
    #pragma unroll
    for (int ks = 0; ks < 2; ++ks)
        #pragma unroll
        for (int ntd = 0; ntd < 2; ++ntd) {
            int d = 16 * ntd + fr;
            bvf[ks][ntd] = ldsv8(&vT[d * 64 + ((32 * ks + 8 * g) ^ ((d & 7) << 3))]);
        }
    v4f o[4][2];
    #pragma unroll
    for (int mt = 0; mt < 4; ++mt) { o[mt][0] = vzero; o[mt][1] = vzero; }
    #pragma unroll
    for (int mt = 0; mt < 4; ++mt) {
        int row = mt * 16 + fr; row = row > 48 ? 48 : row;
        int r7 = row & 7;
        #pragma unroll
        for (int ks = 0; ks < 2; ++ks) {
            v8h ap = ldsv8(&P[row * 64 + ((4 * ks + g) ^ r7) * 8]);
            #pragma unroll
            for (int ntd = 0; ntd < 2; ++ntd)
                o[mt][ntd] = __builtin_amdgcn_mfma_f32_16x16x32_f16(ap, bvf[ks][ntd], o[mt][ntd], 0, 0, 0);
        }
    }
    // ---- store ao[b*49+tok][h*32+d] f16 (32B segments) ----
    _Float16* ob = ao + ((size_t)b * NTOK) * 256 + h * 32;
    #pragma unroll
    for (int mt = 0; mt < 4; ++mt)
        #pragma unroll
        for (int r = 0; r < 4; ++r) {
            int tok = mt * 16 + 4 * g + r;
            if (tok < NTOK) {
                #pragma unroll
                for (int ntd = 0; ntd < 2; ++ntd)
                    ob[tok * 256 + 16 * ntd + fr] = (_Float16)o[mt][ntd][r];
            }
        }
}

// ---------------- K3: out = ao @ Wp^T + bp (proven, v10 verbatim) ----------------
__global__ __launch_bounds__(512) void wa_proj(
    const _Float16* __restrict__ ao, const _Float16* __restrict__ wp,
    const float* __restrict__ bp, float* __restrict__ out) {

    __shared__ _Float16 as[128 * PPAD];

    const int mb   = blockIdx.x;
    const int tid  = threadIdx.x;
    const int wid  = tid >> 6;
    const int lane = tid & 63;
    const int g    = lane >> 4;
    const int fr   = lane & 15;

    const _Float16* ab = ao + (size_t)mb * (128 * 256);
    for (int i = tid; i < (128 * 256) / 8; i += 512) {
        v8h v = *(const v8h*)&ab[i * 8];
        int e = i * 8;
        *(v8h*)&as[(e >> 8) * PPAD + (e & 255)] = v;
    }
    __syncthreads();

    const v4f vzero = {0.f, 0.f, 0.f, 0.f};
    v4f acc[2][8];
    #pragma unroll
    for (int ntl = 0; ntl < 2; ++ntl)
        #pragma unroll
        for (int mt = 0; mt < 8; ++mt) acc[ntl][mt] = vzero;

    #pragma unroll
    for (int ks = 0; ks < 8; ++ks) {
        v8h a[8];
        #pragma unroll
        for (int mt = 0; mt < 8; ++mt)
            a[mt] = ldsv8(&as[(mt * 16 + fr) * PPAD + ks * 32 + g * 8]);
        #pragma unroll
        for (int ntl = 0; ntl < 2; ++ntl) {
            int n = wid * 32 + 16 * ntl + fr;
            v8h bf = *(const v8h*)&wp[n * 256 + ks * 32 + g * 8];
            #pragma unroll
            for (int mt = 0; mt < 8; ++mt)
                acc[ntl][mt] = __builtin_amdgcn_mfma_f32_16x16x32_f16(a[mt], bf, acc[ntl][mt], 0, 0, 0);
        }
    }

    float* ob = out + (size_t)mb * (128 * 256);
    #pragma unroll
    for (int ntl = 0; ntl < 2; ++ntl) {
        int n = wid * 32 + 16 * ntl + fr;
        float bpn = bp[n];
        #pragma unroll
        for (int mt = 0; mt < 8; ++mt)
            #pragma unroll
            for (int r = 0; r < 4; ++r)
                ob[(mt * 16 + 4 * g + r) * 256 + n] = acc[ntl][mt][r] + bpn;
    }
}

extern "C" void kernel_launch(void* const* d_in, const int* in_sizes, int n_in,
                              void* d_out, int out_size, void* d_ws, size_t ws_size,
                              hipStream_t stream) {
    const float* x          = (const float*)d_in[0];
    const float* bias_table = (const float*)d_in[1];
    const float* Wq         = (const float*)d_in[2];
    const float* bq         = (const float*)d_in[3];
    const float* Wk         = (const float*)d_in[4];
    const float* bk         = (const float*)d_in[5];
    const float* Wv         = (const float*)d_in[6];
    const float* bv         = (const float*)d_in[7];
    const float* Wp         = (const float*)d_in[8];
    const float* bp         = (const float*)d_in[9];
    const int*   rel_idx    = (const int*)d_in[10];
    float* out = (float*)d_out;

    // ws layout (bytes):
    //   wqkv f16 [768*256]      @ 0
    //   wp   f16 [256*256]      @ 393216
    //   biasm2 f32 [8*49*16*4]  @ 524288
    //   qg f16 [32768*49*32]    @ 624640      (102,760,448 each)
    //   kg                      @ 624640 + 1*102760448
    //   vg                      @ 624640 + 2*102760448
    //   ao f16 [200704*256]     @ 624640 + 3*102760448     total ~411.7 MB
    _Float16* wqkv   = (_Float16*)d_ws;
    _Float16* wp     = wqkv + 768 * 256;
    float*    biasm2 = (float*)(wp + 256 * 256);
    char*     base   = (char*)d_ws + 624640;
    _Float16* qg = (_Float16*)(base);
    _Float16* kg = (_Float16*)(base + 1ull * 102760448);
    _Float16* vg = (_Float16*)(base + 2ull * 102760448);
    _Float16* ao = (_Float16*)(base + 3ull * 102760448);

    const int TOT = 768 * 256 + 256 * 256 + 8 * NTOK * 16;
    wa_prep<<<(TOT + 255) / 256, 256, 0, stream>>>(Wq, Wk, Wv, Wp, bias_table, rel_idx,
                                                   wqkv, wp, biasm2);
    wa_qkv<<<dim3(3136, 3), 512, 0, stream>>>(x, bq, bk, bv, wqkv, qg, kg, vg);
    wa_attn2<<<8192, 256, 0, stream>>>(qg, kg, vg, biasm2, ao);
    wa_proj<<<1568, 512, 0, stream>>>(ao, wp, bp, out);
}